// Round 1
// baseline (832.135 us; speedup 1.0000x reference)
//
#include <hip/hip_runtime.h>
#include <stdint.h>

#define NROWS 65536
#define IDIM 2048

typedef __attribute__((ext_vector_type(4))) float v4f;
typedef __attribute__((ext_vector_type(4))) short v4s;
typedef __attribute__((ext_vector_type(8))) short v8s;

__device__ __forceinline__ unsigned short f2bf(float f) {
  unsigned int u = __float_as_uint(f);
  u += 0x7fffu + ((u >> 16) & 1u);          // round-to-nearest-even
  return (unsigned short)(u >> 16);
}
__device__ __forceinline__ float bf2f(unsigned short h) {
  return __uint_as_float(((unsigned int)h) << 16);
}

struct Expert {
  const unsigned short* w1t;   // [HN][2048] bf16
  const float* b1;
  const unsigned short* w2t;   // [HN/2][HN] bf16
  const float* b2;
  const float* w3;             // [HN/2]
  const float* b3;             // [1]
  const int* idx;              // this expert's row-index list
  const int* count;
};
struct Quad { Expert e[4]; };

// ---------------- prep kernel 1: bucket rows by label ----------------
__global__ void build_lists(const int* __restrict__ labels, float* __restrict__ out,
                            int* __restrict__ counts, int* __restrict__ idx, int n)
{
  __shared__ int lcnt[4];
  __shared__ int lbase[4];
  const int t = threadIdx.x;
  if (t < 4) lcnt[t] = 0;
  __syncthreads();
  const int i = blockIdx.x * blockDim.x + t;
  int lbl = -1, pos = 0;
  if (i < n) {
    lbl = labels[i];
    if (lbl >= 0 && lbl <= 3) {
      pos = atomicAdd(&lcnt[lbl], 1);
    } else {
      out[i] = 0.f;   // rows with unknown label output 0 (d_out is poisoned)
      lbl = -1;
    }
  }
  __syncthreads();
  if (t < 4) lbase[t] = atomicAdd(&counts[t], lcnt[t]);
  __syncthreads();
  if (lbl >= 0) idx[lbl * NROWS + lbase[lbl] + pos] = i;
}

// ---------------- prep kernel 2: transpose + fp32->bf16 weights ----------------
__global__ void conv_w(const float* __restrict__ W1, const float* __restrict__ W2,
                       unsigned short* __restrict__ w1t, unsigned short* __restrict__ w2t,
                       int HN, int total)
{
  const int n1 = IDIM * HN;
  const int HN2 = HN >> 1;
  int i = blockIdx.x * blockDim.x + threadIdx.x;
  if (i >= total) return;
  if (i < n1) {
    int nn = i / IDIM, k = i - nn * IDIM;
    w1t[i] = f2bf(W1[k * HN + nn]);        // w1t[n][k] = W1[k][n]
  } else {
    int j = i - n1;
    int nn = j / HN, k = j - nn * HN;
    w2t[j] = f2bf(W2[k * HN2 + nn]);       // w2t[n][k] = W2[k][n]
  }
}

// ---------------- main fused kernel ----------------
// LDS budget (HN=128 instantiation, the max): A(128x40) + B(128x40) + h1(128x136)
// in bf16 + 128 ints = 55808 B -> 2 blocks/CU. W2T and h2 alias the dead A/B region.
template<int HN>
__device__ __forceinline__ void moe_body(const float* __restrict__ x, float* __restrict__ out,
                                         const Expert E, char* smem)
{
  constexpr int HN2 = HN / 2;
  constexpr int TM = 128, BK = 32;
  constexpr int AW  = BK + 8;     // LDS row stride (elements), 16B-multiple
  constexpr int H1W = HN + 8;
  constexpr int H2W = HN2 + 4;
  constexpr int NF1 = HN / 16;
  constexpr int NF2 = HN2 / 16;

  unsigned short* sA  = (unsigned short*)smem;   // [TM][AW]
  unsigned short* sB  = sA + TM * AW;            // [HN][AW]
  unsigned short* sH1 = sB + HN * AW;            // [TM][H1W]
  int* sRid = (int*)(sH1 + (size_t)TM * H1W);    // [TM]
  unsigned short* sW2 = sA;                      // [HN2][H1W]  aliases A+B region
  unsigned short* sH2 = sA;                      // [TM][H2W]   aliases after extra sync

  const int cnt = *E.count;
  const int tile0 = blockIdx.x * TM;
  if (tile0 >= cnt) return;
  const int rv = min(TM, cnt - tile0);

  const int t    = threadIdx.x;
  const int lane = t & 63;
  const int l15  = lane & 15;
  const int quad = lane >> 4;
  const int m0w  = (t >> 6) * 32;   // wave's first row

  if (t < TM) sRid[t] = E.idx[tile0 + ((t < rv) ? t : 0)];
  __syncthreads();

  // Each thread stages 4 float4 chunks of A per K-step; row assignment is fixed.
  const float* aptr[4];
  {
    const int c4 = (t & 7) * 4;
    #pragma unroll
    for (int i = 0; i < 4; ++i) {
      const int r = i * 32 + (t >> 3);
      aptr[i] = x + (size_t)sRid[r] * IDIM + c4;
    }
  }

  v4f acc[2][NF1];
  #pragma unroll
  for (int mi = 0; mi < 2; ++mi)
    #pragma unroll
    for (int ni = 0; ni < NF1; ++ni)
      acc[mi][ni] = (v4f){0.f, 0.f, 0.f, 0.f};

  constexpr int BIT = (HN * BK / 8) / 256;  // 16B B-chunks per thread (2 or 1)

  for (int k0 = 0; k0 < IDIM; k0 += BK) {
    // stage A: gathered x rows, fp32 -> bf16
    #pragma unroll
    for (int i = 0; i < 4; ++i) {
      v4f v = *(const v4f*)(aptr[i] + k0);
      const int r = i * 32 + (t >> 3);
      v4s pk;
      pk[0] = (short)f2bf(v[0]); pk[1] = (short)f2bf(v[1]);
      pk[2] = (short)f2bf(v[2]); pk[3] = (short)f2bf(v[3]);
      *(v4s*)&sA[r * AW + (t & 7) * 4] = pk;
    }
    // stage B: W1T tile (already bf16, [n][k])
    #pragma unroll
    for (int i = 0; i < BIT; ++i) {
      const int c = i * 256 + t;
      const int nn = c >> 2, c8 = (c & 3) * 8;
      *(v8s*)&sB[nn * AW + c8] = *(const v8s*)(E.w1t + (size_t)nn * IDIM + k0 + c8);
    }
    __syncthreads();
    v8s a[2], b[NF1];
    #pragma unroll
    for (int mi = 0; mi < 2; ++mi)
      a[mi] = *(const v8s*)&sA[(m0w + mi * 16 + l15) * AW + quad * 8];
    #pragma unroll
    for (int ni = 0; ni < NF1; ++ni)
      b[ni] = *(const v8s*)&sB[(ni * 16 + l15) * AW + quad * 8];
    #pragma unroll
    for (int mi = 0; mi < 2; ++mi)
      #pragma unroll
      for (int ni = 0; ni < NF1; ++ni)
        acc[mi][ni] = __builtin_amdgcn_mfma_f32_16x16x32_bf16(a[mi], b[ni], acc[mi][ni], 0, 0, 0);
    __syncthreads();
  }

  // epilogue 1: h1 = relu(acc + b1) -> LDS bf16 [row][col]
  #pragma unroll
  for (int mi = 0; mi < 2; ++mi) {
    #pragma unroll
    for (int ni = 0; ni < NF1; ++ni) {
      const int col = ni * 16 + l15;
      const float b1v = E.b1[col];
      #pragma unroll
      for (int r = 0; r < 4; ++r) {
        const int row = m0w + mi * 16 + quad * 4 + r;
        sH1[row * H1W + col] = f2bf(fmaxf(acc[mi][ni][r] + b1v, 0.f));
      }
    }
  }
  // stage W2T into dead A/B region
  {
    constexpr int CH = HN2 * HN / 8;    // 16B chunks (divisible by 256)
    #pragma unroll
    for (int i = 0; i < CH / 256; ++i) {
      const int c = i * 256 + t;
      const int nn = c / (HN / 8), kc = (c % (HN / 8)) * 8;
      *(v8s*)&sW2[nn * H1W + kc] = *(const v8s*)(E.w2t + nn * HN + kc);
    }
  }
  __syncthreads();

  // layer 2: h2 = relu(h1 @ W2 + b2), MFMA, K = HN
  v4f acc2[2][NF2];
  #pragma unroll
  for (int mi = 0; mi < 2; ++mi)
    #pragma unroll
    for (int ni = 0; ni < NF2; ++ni)
      acc2[mi][ni] = (v4f){0.f, 0.f, 0.f, 0.f};
  #pragma unroll
  for (int ks = 0; ks < HN / 32; ++ks) {
    v8s a2[2], b2[NF2];
    #pragma unroll
    for (int mi = 0; mi < 2; ++mi)
      a2[mi] = *(const v8s*)&sH1[(m0w + mi * 16 + l15) * H1W + ks * 32 + quad * 8];
    #pragma unroll
    for (int ni = 0; ni < NF2; ++ni)
      b2[ni] = *(const v8s*)&sW2[(ni * 16 + l15) * H1W + ks * 32 + quad * 8];
    #pragma unroll
    for (int mi = 0; mi < 2; ++mi)
      #pragma unroll
      for (int ni = 0; ni < NF2; ++ni)
        acc2[mi][ni] = __builtin_amdgcn_mfma_f32_16x16x32_bf16(a2[mi], b2[ni], acc2[mi][ni], 0, 0, 0);
  }
  __syncthreads();   // all W2T reads done before h2 overwrites that region

  // epilogue 2: h2 -> LDS bf16 [row][col]
  #pragma unroll
  for (int mi = 0; mi < 2; ++mi) {
    #pragma unroll
    for (int ni = 0; ni < NF2; ++ni) {
      const int col = ni * 16 + l15;
      const float b2v = E.b2[col];
      #pragma unroll
      for (int r = 0; r < 4; ++r) {
        const int row = m0w + mi * 16 + quad * 4 + r;
        sH2[row * H2W + col] = f2bf(fmaxf(acc2[mi][ni][r] + b2v, 0.f));
      }
    }
  }
  __syncthreads();

  // layer 3: out = h2 @ W3 + b3 (scalar dot, length HN/2)
  if (t < rv) {
    float a3 = E.b3[0];
    #pragma unroll
    for (int j = 0; j < HN2; ++j)
      a3 = fmaf(bf2f(sH2[t * H2W + j]), E.w3[j], a3);
    out[sRid[t]] = a3;
  }
}

__global__ __launch_bounds__(256, 2)
void moe_main(const float* __restrict__ x, float* __restrict__ out, Quad q)
{
  __shared__ __align__(16) char smem[55808];
  const int e = blockIdx.y;
  if (e < 2) moe_body<64>(x, out, q.e[e], smem);
  else       moe_body<128>(x, out, q.e[e], smem);
}

// ---------------- host ----------------
extern "C" void kernel_launch(void* const* d_in, const int* in_sizes, int n_in,
                              void* d_out, int out_size, void* d_ws, size_t ws_size,
                              hipStream_t stream)
{
  const float* x   = (const float*)d_in[0];
  const int* labels = (const int*)d_in[1];
  float* out = (float*)d_out;

  char* ws = (char*)d_ws;
  int* counts = (int*)ws;                       // 16 B
  int* idx = (int*)(ws + 256);                  // 4 * 65536 ints = 1 MiB
  static const int HNs[4] = {64, 64, 128, 128};
  unsigned short* w1t[4];
  unsigned short* w2t[4];
  size_t off = 256 + (size_t)4 * NROWS * 4;
  for (int e = 0; e < 4; ++e) { w1t[e] = (unsigned short*)(ws + off); off += (size_t)IDIM * HNs[e] * 2; }
  for (int e = 0; e < 4; ++e) { w2t[e] = (unsigned short*)(ws + off); off += (size_t)HNs[e] * (HNs[e] / 2) * 2; }

  hipMemsetAsync(counts, 0, 4 * sizeof(int), stream);
  build_lists<<<dim3(NROWS / 256), dim3(256), 0, stream>>>(labels, out, counts, idx, NROWS);
  for (int e = 0; e < 4; ++e) {
    const int total = IDIM * HNs[e] + HNs[e] * (HNs[e] / 2);
    const float* W1 = (const float*)d_in[2 + 6 * e + 0];
    const float* W2 = (const float*)d_in[2 + 6 * e + 2];
    conv_w<<<dim3((total + 255) / 256), dim3(256), 0, stream>>>(W1, W2, w1t[e], w2t[e], HNs[e], total);
  }
  Quad q;
  for (int e = 0; e < 4; ++e) {
    q.e[e].w1t = w1t[e];
    q.e[e].b1  = (const float*)d_in[2 + 6 * e + 1];
    q.e[e].w2t = w2t[e];
    q.e[e].b2  = (const float*)d_in[2 + 6 * e + 3];
    q.e[e].w3  = (const float*)d_in[2 + 6 * e + 4];
    q.e[e].b3  = (const float*)d_in[2 + 6 * e + 5];
    q.e[e].idx = idx + (size_t)e * NROWS;
    q.e[e].count = counts + e;
  }
  moe_main<<<dim3(NROWS / 128, 4), dim3(256), 0, stream>>>(x, out, q);
}